// Round 1
// baseline (673.228 us; speedup 1.0000x reference)
//
#include <hip/hip_runtime.h>

#define NTASK 2048
#define NQ 75
#define NS 25
#define DD 640
#define NW 5
#define RIDGE 50.0f
#define CH 80          // k-chunk width for gram staging
#define CSTRIDE 84     // padded LDS row stride (banks: 84%32=20, spreads rows 0,5,10,15,20)

__global__ __launch_bounds__(256) void r2d2_fused(
    const float* __restrict__ query,    // [B][75][640]
    const float* __restrict__ support,  // [B][25][640]
    const int*   __restrict__ labels,   // [B][25]
    float* __restrict__ out)            // [B][75][5]
{
    // LDS plan (floats):
    //  phase A/B: chunk [0,2100) | red [2100,4600) | gram [4600,5225) | sol [5225,5350)
    //  phase D/E: Wsm [0,3200) overlays dead chunk+red head; sol stays live at 5225+
    __shared__ __align__(16) float smem[5360];
    float* chunk = smem;
    float* red   = smem + 2100;
    float* gram  = smem + 4600;
    float* sol   = smem + 5225;
    float* Wsm   = smem;

    const int task = blockIdx.x;
    const int t    = threadIdx.x;
    const int lane = t & 63;
    const int wv   = t >> 6;

    const float* S = support + (size_t)task * (NS * DD);

    // ---- Phase A: gram = S S^T, register-tiled ----
    // thread = (sub, tile): sub = d-slice (8 of 10 within chunk... 8 subs x 10k), tile = 5x5 block
    const int sub  = t >> 5;          // 0..7
    const int tile = t & 31;          // 0..31 (active < 25)
    const int ti   = tile / 5;
    const int tj   = tile - 5 * ti;

    float acc[5][5];
    #pragma unroll
    for (int a = 0; a < 5; ++a)
        #pragma unroll
        for (int b = 0; b < 5; ++b) acc[a][b] = 0.f;

    for (int c = 0; c < DD / CH; ++c) {
        __syncthreads();  // protect chunk from previous iteration's readers
        for (int e = t; e < (NS * CH) / 4; e += 256) {   // 500 float4
            const int i = e / (CH / 4);
            const int m = (e - i * (CH / 4)) * 4;
            const float4 v = *reinterpret_cast<const float4*>(S + i * DD + c * CH + m);
            *reinterpret_cast<float4*>(&chunk[i * CSTRIDE + m]) = v;
        }
        __syncthreads();
        if (tile < 25) {
            #pragma unroll
            for (int m = 0; m < 10; ++m) {
                const int kk = sub * 10 + m;
                float av[5], bv[5];
                #pragma unroll
                for (int a = 0; a < 5; ++a) av[a] = chunk[(ti * 5 + a) * CSTRIDE + kk];
                #pragma unroll
                for (int b = 0; b < 5; ++b) bv[b] = chunk[(tj * 5 + b) * CSTRIDE + kk];
                #pragma unroll
                for (int a = 0; a < 5; ++a)
                    #pragma unroll
                    for (int b = 0; b < 5; ++b)
                        acc[a][b] = fmaf(av[a], bv[b], acc[a][b]);
            }
        }
    }

    // ---- Phase B: reduce 8 sub-partials -> gram in LDS ----
    // lanes l and l^32 share a tile (subs 2v,2v+1): one shuffle folds wave to 1 partial
    #pragma unroll
    for (int a = 0; a < 5; ++a)
        #pragma unroll
        for (int b = 0; b < 5; ++b)
            acc[a][b] += __shfl_xor(acc[a][b], 32);
    if (lane < 25) {   // lane == tile here
        #pragma unroll
        for (int a = 0; a < 5; ++a)
            #pragma unroll
            for (int b = 0; b < 5; ++b)
                red[wv * 625 + (ti * 5 + a) * 25 + (tj * 5 + b)] = acc[a][b];
    }
    __syncthreads();
    for (int e = t; e < 625; e += 256) {
        float g = red[e] + red[625 + e] + red[1250 + e] + red[1875 + e];
        const int r  = e / 25;
        const int cc = e - 25 * r;
        if (r == cc) g += RIDGE;
        gram[e] = g;
    }
    __syncthreads();

    // ---- Phase C: Gauss-Jordan solve on wave 0; lane = column of [gram | Y] ----
    if (t < 64) {
        const int cl = t;          // columns 0..24 = gram, 25..29 = one-hot Y
        float a[NS];
        if (cl < NS) {
            #pragma unroll
            for (int r = 0; r < NS; ++r) a[r] = gram[r * 25 + cl];
        } else if (cl < NS + NW) {
            const int w = cl - NS;
            #pragma unroll
            for (int r = 0; r < NS; ++r)
                a[r] = (labels[task * NS + r] == w) ? 1.f : 0.f;
        } else {
            #pragma unroll
            for (int r = 0; r < NS; ++r) a[r] = 0.f;
        }
        #pragma unroll
        for (int p = 0; p < NS; ++p) {
            const float App = __shfl(a[p], p);
            const float inv = 1.0f / App;
            #pragma unroll
            for (int r = 0; r < NS; ++r) {
                if (r != p) {
                    const float Arp = __shfl(a[r], p);
                    a[r] = fmaf(-Arp * inv, a[p], a[r]);
                }
            }
        }
        #pragma unroll
        for (int r = 0; r < NS; ++r) {
            const float Dr = __shfl(a[r], r);
            const float s  = a[r] / Dr;
            if (cl >= NS && cl < NS + NW) sol[r * NW + (cl - NS)] = s;
        }
    }
    __syncthreads();

    // ---- Phase D: W = S^T sol -> Wsm[w][k] (S re-read, column-coalesced, L2-warm) ----
    for (int k = t; k < DD; k += 256) {
        float a5[NW] = {0.f, 0.f, 0.f, 0.f, 0.f};
        #pragma unroll
        for (int i = 0; i < NS; ++i) {
            const float sv = S[i * DD + k];
            #pragma unroll
            for (int w = 0; w < NW; ++w) a5[w] = fmaf(sv, sol[i * NW + w], a5[w]);
        }
        #pragma unroll
        for (int w = 0; w < NW; ++w) Wsm[w * DD + k] = a5[w];
    }
    __syncthreads();

    // ---- Phase E: logits = Q W. Per-lane W cache: k = 4*lane + 256*c (60 VGPRs) ----
    float4 wr[NW][3];
    const float4* W4 = reinterpret_cast<const float4*>(Wsm);
    #pragma unroll
    for (int w = 0; w < NW; ++w) {
        wr[w][0] = W4[w * 160 + lane];
        wr[w][1] = W4[w * 160 + 64 + lane];
        wr[w][2] = (lane < 32) ? W4[w * 160 + 128 + lane] : make_float4(0.f, 0.f, 0.f, 0.f);
    }
    const float4* Q4 = reinterpret_cast<const float4*>(query + (size_t)task * (NQ * DD));
    float* outp = out + (size_t)task * (NQ * NW);

    for (int row = wv; row < NQ; row += 4) {
        const float4* Qr = Q4 + row * 160;
        const float4 qa = Qr[lane];
        const float4 qb = Qr[64 + lane];
        const float4 qc = (lane < 32) ? Qr[128 + lane] : make_float4(0.f, 0.f, 0.f, 0.f);
        float accw[NW];
        #pragma unroll
        for (int w = 0; w < NW; ++w) {
            float v;
            v = qa.x * wr[w][0].x;
            v = fmaf(qa.y, wr[w][0].y, v);
            v = fmaf(qa.z, wr[w][0].z, v);
            v = fmaf(qa.w, wr[w][0].w, v);
            v = fmaf(qb.x, wr[w][1].x, v);
            v = fmaf(qb.y, wr[w][1].y, v);
            v = fmaf(qb.z, wr[w][1].z, v);
            v = fmaf(qb.w, wr[w][1].w, v);
            v = fmaf(qc.x, wr[w][2].x, v);
            v = fmaf(qc.y, wr[w][2].y, v);
            v = fmaf(qc.z, wr[w][2].z, v);
            v = fmaf(qc.w, wr[w][2].w, v);
            accw[w] = v;
        }
        // 64-lane butterfly reduce for each of the 5 outputs
        #pragma unroll
        for (int w = 0; w < NW; ++w) {
            float v = accw[w];
            v += __shfl_xor(v, 1);
            v += __shfl_xor(v, 2);
            v += __shfl_xor(v, 4);
            v += __shfl_xor(v, 8);
            v += __shfl_xor(v, 16);
            v += __shfl_xor(v, 32);
            accw[w] = v;
        }
        if (lane == 0) {
            #pragma unroll
            for (int w = 0; w < NW; ++w) outp[row * NW + w] = accw[w];
        }
    }
}

extern "C" void kernel_launch(void* const* d_in, const int* in_sizes, int n_in,
                              void* d_out, int out_size, void* d_ws, size_t ws_size,
                              hipStream_t stream) {
    const float* query   = (const float*)d_in[0];
    const float* support = (const float*)d_in[1];
    const int*   labels  = (const int*)d_in[2];
    float* out = (float*)d_out;

    hipLaunchKernelGGL(r2d2_fused, dim3(NTASK), dim3(256), 0, stream,
                       query, support, labels, out);
}